// Round 14
// baseline (209.357 us; speedup 1.0000x reference)
//
#include <hip/hip_runtime.h>

typedef __bf16 bf16x8 __attribute__((ext_vector_type(8)));
typedef short  s16x8  __attribute__((ext_vector_type(8)));
typedef float  f32x4  __attribute__((ext_vector_type(4)));

#define DEVINL __device__ __forceinline__

DEVINL unsigned short f2bf(float f) {
  unsigned int u = __builtin_bit_cast(unsigned int, f);
  u += 0x7fffu + ((u >> 16) & 1u);   // round-to-nearest-even
  return (unsigned short)(u >> 16);
}

DEVINL void async16(const void* g, void* l) {
  __builtin_amdgcn_global_load_lds(
      (const __attribute__((address_space(1))) unsigned int*)g,
      (__attribute__((address_space(3))) unsigned int*)l, 16, 0, 0);
}

// ---------------- fused prep kernel ----------------

__global__ __launch_bounds__(256) void prep(
    const float* __restrict__ x, const float* __restrict__ W1,
    const float* __restrict__ W2, const float* __restrict__ theta,
    const float* __restrict__ wre, const float* __restrict__ wim,
    unsigned short* __restrict__ xb, unsigned short* __restrict__ w1t,
    unsigned short* __restrict__ w2t, float* __restrict__ c1) {
  __shared__ unsigned short tile[32][33];
  const int b = blockIdx.x;
  const int tid = threadIdx.x;
  if (b < 1024) {
    int i = b * 256 + tid;
#pragma unroll
    for (int k = 0; k < 8; ++k, i += 262144) {
      float4 v = ((const float4*)x)[i];
      ushort4 o;
      o.x = f2bf(v.x); o.y = f2bf(v.y); o.z = f2bf(v.z); o.w = f2bf(v.w);
      ((ushort4*)xb)[i] = o;
    }
  } else if (b < 5120) {
    int bb = b - 1024;                      // W1: R=1024, C=4096
    int bc = (bb & 127) * 32, br = (bb >> 7) * 32;
    int tx = tid & 31, ty = tid >> 5;
#pragma unroll
    for (int i = 0; i < 32; i += 8)
      tile[ty + i][tx] = f2bf(W1[(size_t)(br + ty + i) * 4096 + (bc + tx)]);
    __syncthreads();
#pragma unroll
    for (int i = 0; i < 32; i += 8)
      w1t[(size_t)(bc + ty + i) * 1024 + (br + tx)] = tile[tx][ty + i];
  } else if (b < 9216) {
    int bb = b - 5120;                      // W2: R=4096, C=1024
    int bc = (bb & 31) * 32, br = (bb >> 5) * 32;
    int tx = tid & 31, ty = tid >> 5;
#pragma unroll
    for (int i = 0; i < 32; i += 8)
      tile[ty + i][tx] = f2bf(W2[(size_t)(br + ty + i) * 1024 + (bc + tx)]);
    __syncthreads();
#pragma unroll
    for (int i = 0; i < 32; i += 8)
      w2t[(size_t)(bc + ty + i) * 4096 + (br + tx)] = tile[tx][ty + i];
  } else {
    int i = (b - 9216) * 256 + tid;         // qconst, n = 4096
    float t = theta[i];
    c1[i] = (cosf(t) * wre[i] + sinf(t) * wim[i]) * wim[i] * 0.1f;
  }
}

// ================= GEMM1: actb = relu(qt(xb @ w1t^T + b1)) =================
// 256x256 tile, BK=64, NT=16, REPS=2. R14: skewed-register pipeline (R6
// structure, spill cause removed via launch_bounds(512,1) -> 256 VGPR).
// Every MFMA cluster consumes fragments loaded in a PREVIOUS window:
//  WIN_A(T,P): read b[4][2], a1 of tile T (16 reads); QUAD(a0,·) uses a0
//    preloaded in WIN_B(T-1) -> only b-reads gate, a1/b1 reads overlap MFMA;
//    lgkm0 (my buf-P reads done); vmcnt(0) certifies tile T+1 (staged in
//    WIN_B(T-1), ~1 window of latency hiding); BAR.
//  WIN_B(T,P): stage tile T+2 -> buf P (8 loads; WAR-safe: buf P's A0 read
//    drained at WIN_B(T-1) lgkm0, A1+B at WIN_A(T) lgkm0, all before their
//    BARs); read a0(T+1) from buf P^1 (certified); QUAD(a1,·) is 100%
//    register-fed -> overlaps the stage issue + a0 reads; lgkm0; BAR.
// Registers: acc 128 + a0/a1/b 96 + addr ~20 = ~244 < 256.
// Rep boundary: stage next-rep tile0+tile1 (16 loads) BEFORE epilogue;
//  vmcnt(16) after (FIFO: 16 loads oldest, 16 epilogue stores newest);
//  BAR; preload a0.

__global__ __launch_bounds__(512, 1) void gemm1k(
    const unsigned short* __restrict__ A,    // xb  [8192][1024]
    const unsigned short* __restrict__ Bt,   // w1t [4096][1024]
    const float* __restrict__ bias,
    const float* __restrict__ theta,
    const float* __restrict__ c1,
    unsigned short* __restrict__ Cout) {     // actb [8192][4096]
  constexpr int K = 1024, N = 4096, NT = 16, REPS = 2;
  constexpr int WROWS = 128, M_REP = 8, MH = 4;
  constexpr int ABYTES = 32768, AH = 16384, AL = 2;
  constexpr int BUFSZ = 65536;
  constexpr int nTilesN = 8;                 // 4096 / 512

  __shared__ __align__(16) char lds[2 * BUFSZ + 16384];

  int nwg = gridDim.x;
  int wg = blockIdx.x;
  int sw = (wg & 7) * (nwg >> 3) + (wg >> 3);
  int rowBase = (sw / nTilesN) * 256;
  int colBase = (sw % nTilesN) * 512;

  const int t = threadIdx.x;
  const int lane = t & 63;
  const int wid = t >> 6;
  const int wr = wid >> 2, wc = wid & 3;
  const int lr = lane & 15;
  const int lg = lane >> 4;
  const int r7 = lane & 7;

  const int srow = t >> 3;
  const int scolB = ((t & 7) * 16) ^ ((srow & 7) << 4);
  const unsigned short* aSrcB = A  + (size_t)(rowBase + srow) * K + (scolB >> 1);
  const unsigned short* bSrcB = Bt + (size_t)(colBase + srow) * K + (scolB >> 1);

  const int aRd = (wr * WROWS + lr) * 128 + ((lg ^ r7) << 4);
  const int bRd = ABYTES + (wc * 64 + lr) * 128 + ((lg ^ r7) << 4);

#define STAGE_AU(S, U, P) do {                                              \
    _Pragma("unroll") for (int j = 0; j < AL; ++j)                          \
      async16(aSrcB + ((size_t)((U) * WROWS + j * 64) * K + (size_t)(S) * 64),\
              &lds[(P) * BUFSZ + (U) * AH + j * 8192 + t * 16]);            \
  } while (0)
#define STAGE_BU(SRC, S, U, P) do {                                         \
    _Pragma("unroll") for (int j = 0; j < 2; ++j)                           \
      async16((SRC) + ((size_t)((U) * 128 + j * 64) * K + (size_t)(S) * 64),\
              &lds[(P) * BUFSZ + ABYTES + (U) * 16384 + j * 8192 + t * 16]);\
  } while (0)
#define LOAD_A0(P)                                                          \
  _Pragma("unroll") for (int mi = 0; mi < MH; ++mi)                         \
  _Pragma("unroll") for (int ks = 0; ks < 2; ++ks)                          \
    a0[mi][ks] = __builtin_bit_cast(bf16x8, *(const s16x8*)&lds[            \
        (P) * BUFSZ + ((aRd + mi * 2048) ^ (ks << 6))])
#define LOAD_A1(P)                                                          \
  _Pragma("unroll") for (int mi = 0; mi < MH; ++mi)                         \
  _Pragma("unroll") for (int ks = 0; ks < 2; ++ks)                          \
    a1[mi][ks] = __builtin_bit_cast(bf16x8, *(const s16x8*)&lds[            \
        (P) * BUFSZ + ((aRd + (MH + mi) * 2048) ^ (ks << 6))])
#define LOAD_B(NHh, P)                                                      \
  _Pragma("unroll") for (int nn = 0; nn < 2; ++nn)                          \
  _Pragma("unroll") for (int ks = 0; ks < 2; ++ks)                          \
    b[(NHh) * 2 + nn][ks] = __builtin_bit_cast(bf16x8, *(const s16x8*)&lds[ \
        (P) * BUFSZ + ((bRd + ((NHh) * 2 + nn) * 2048) ^ (ks << 6))])
#define QUAD(AF, MOFF, NHh)                                                 \
  __builtin_amdgcn_s_setprio(1);                                            \
  _Pragma("unroll") for (int mi = 0; mi < MH; ++mi)                         \
  _Pragma("unroll") for (int nn = 0; nn < 2; ++nn)                          \
  _Pragma("unroll") for (int ks = 0; ks < 2; ++ks)                          \
    acc[(MOFF) + mi][(NHh) * 2 + nn] =                                      \
        __builtin_amdgcn_mfma_f32_16x16x32_bf16(                            \
            AF[mi][ks], b[(NHh) * 2 + nn][ks],                              \
            acc[(MOFF) + mi][(NHh) * 2 + nn], 0, 0, 0);                     \
  __builtin_amdgcn_s_setprio(0)
#define BAR() __builtin_amdgcn_s_barrier()
#define LG0() asm volatile("s_waitcnt lgkmcnt(0)" ::: "memory")
#define WIN_A(T, P) do {                                                    \
    LOAD_B(0, P); LOAD_B(1, P);                                             \
    LOAD_A1(P);                                                             \
    QUAD(a0, 0, 0);                                                         \
    QUAD(a0, 0, 1);                                                         \
    LG0();                                                                  \
    asm volatile("s_waitcnt vmcnt(0)" ::: "memory");                        \
    BAR();                                                                  \
  } while (0)
#define WIN_B(T, P) do {                                                    \
    if ((T) + 2 < NT) {                                                     \
      STAGE_AU((T) + 2, 0, P); STAGE_AU((T) + 2, 1, P);                     \
      STAGE_BU(bSrcR, (T) + 2, 0, P); STAGE_BU(bSrcR, (T) + 2, 1, P);       \
    }                                                                       \
    if ((T) + 1 < NT) LOAD_A0((P) ^ 1);                                     \
    QUAD(a1, MH, 0);                                                        \
    QUAD(a1, MH, 1);                                                        \
    LG0(); BAR();                                                           \
  } while (0)

  // prologue: stage tile0 -> buf0, tile1 -> buf1 (8 loads each)
  {
    const unsigned short* bSrcR = bSrcB;
    STAGE_AU(0, 0, 0); STAGE_AU(0, 1, 0);
    STAGE_BU(bSrcR, 0, 0, 0); STAGE_BU(bSrcR, 0, 1, 0);
    STAGE_AU(1, 0, 1); STAGE_AU(1, 1, 1);
    STAGE_BU(bSrcR, 1, 0, 1); STAGE_BU(bSrcR, 1, 1, 1);
  }
  asm volatile("s_waitcnt vmcnt(8)" ::: "memory");   // tile0 landed
  BAR();

  for (int rep = 0; rep < REPS; ++rep) {
    const unsigned short* bSrcR = bSrcB + (size_t)rep * 256 * K;
    f32x4 acc[M_REP][4] = {};
    bf16x8 a0[MH][2], a1[MH][2], b[4][2];

    LOAD_A0(0);                               // preload a0 of tile0 (buf0)

    for (int T = 0; T < NT; T += 2) {
      WIN_A(T, 0);
      WIN_B(T, 0);
      WIN_A(T + 1, 1);
      WIN_B(T + 1, 1);
    }

    // boundary staging for next rep (hides under epilogue)
    if (rep + 1 < REPS) {
      const unsigned short* bSrcN = bSrcB + (size_t)(rep + 1) * 256 * K;
      STAGE_AU(0, 0, 0); STAGE_AU(0, 1, 0);
      STAGE_BU(bSrcN, 0, 0, 0); STAGE_BU(bSrcN, 0, 1, 0);
      STAGE_AU(1, 0, 1); STAGE_AU(1, 1, 1);
      STAGE_BU(bSrcN, 1, 0, 1); STAGE_BU(bSrcN, 1, 1, 1);
    }

    // ---- fused epilogue (bias + quantum + relu), full-line bf16 stores ----
    const int colR = colBase + rep * 256;
    const int ocol0 = colR + wc * 64 + lr;
    float bvv[4], thv[4], ccv[4];
#pragma unroll
    for (int ni = 0; ni < 4; ++ni) {
      int n = ocol0 + ni * 16;
      bvv[ni] = bias[n]; thv[ni] = theta[n]; ccv[ni] = c1[n];
    }
    const int SB = 2 * BUFSZ + wid * 2048;
    const size_t growB = (size_t)(rowBase + wr * WROWS) * N;
    const int rd = lane >> 3;                // 0..7
    const int bo = (lane & 7) * 16;          // 0..112
#pragma unroll
    for (int mi = 0; mi < M_REP; ++mi) {
#pragma unroll
      for (int ni = 0; ni < 4; ++ni) {
#pragma unroll
        for (int r = 0; r < 4; ++r) {
          int row16 = lg * 4 + r;
          float h = acc[mi][ni][r] + bvv[ni];
          float q = h + ccv[ni] * __sinf(thv[ni] + 0.1f * h);
          unsigned short v = f2bf(fmaxf(q, 0.f));
          int ad = SB + row16 * 128 +
                   (((ni * 16 + lr) * 2) ^ ((row16 & 7) << 4));
          *(unsigned short*)&lds[ad] = v;
        }
      }
      s16x8 w0 = *(const s16x8*)&lds[SB + rd * 128 + (bo ^ ((rd & 7) << 4))];
      s16x8 w1 = *(const s16x8*)&lds[SB + (rd + 8) * 128 +
                                     (bo ^ ((rd & 7) << 4))];
      unsigned short* dst = Cout + growB + (size_t)(mi * 16 + rd) * N +
                            colR + wc * 64 + (lane & 7) * 8;
      *(s16x8*)dst = w0;
      *(s16x8*)(dst + (size_t)8 * N) = w1;   // rows rd and rd+8
    }

    if (rep + 1 < REPS) {
      // FIFO: [16 boundary loads, 16 epilogue stores] -> drain loads only
      asm volatile("s_waitcnt vmcnt(16)" ::: "memory");
      BAR();
    }
  }
#undef WIN_A
#undef WIN_B
#undef QUAD
#undef LOAD_A0
#undef LOAD_A1
#undef LOAD_B
#undef STAGE_AU
#undef STAGE_BU
#undef BAR
#undef LG0
}

// ================= GEMM2: out = actb @ w2t^T + b2 (fp32) =================
// 128x256 tile, BK=64, NT=64 — UNCHANGED from R13 (measured at its LDS-pipe
// floor: 2738 cy/tile vs reads 2304 + stage-writes 384 = 2688).

__global__ __launch_bounds__(512, 1) void gemm2k(
    const unsigned short* __restrict__ A,    // actb [8192][4096]
    const unsigned short* __restrict__ Bt,   // w2t  [1024][4096]
    const float* __restrict__ bias,
    float* __restrict__ Cout) {              // out [8192][1024]
  constexpr int K = 4096, N = 1024, NT = 64;
  constexpr int WROWS = 64, M_REP = 4, MH = 2;
  constexpr int ABYTES = 16384, AH = 8192, AL = 1;
  constexpr int BUFSZ = 49152;
  constexpr int nTilesN = 4;

  __shared__ __align__(16) char lds[2 * BUFSZ + 32768];

  int nwg = gridDim.x;
  int wg = blockIdx.x;
  int sw = (wg & 7) * (nwg >> 3) + (wg >> 3);
  int rowBase = (sw / nTilesN) * 128;
  int colBase = (sw % nTilesN) * 256;

  const int t = threadIdx.x;
  const int lane = t & 63;
  const int wid = t >> 6;
  const int wr = wid >> 2, wc = wid & 3;
  const int lr = lane & 15;
  const int lg = lane >> 4;
  const int r7 = lane & 7;

  const int srow = t >> 3;
  const int scolB = ((t & 7) * 16) ^ ((srow & 7) << 4);
  const unsigned short* aSrcB = A  + (size_t)(rowBase + srow) * K + (scolB >> 1);
  const unsigned short* bSrcB = Bt + (size_t)(colBase + srow) * K + (scolB >> 1);

  const int aRd = (wr * WROWS + lr) * 128 + ((lg ^ r7) << 4);
  const int bRd = ABYTES + (wc * 64 + lr) * 128 + ((lg ^ r7) << 4);

  f32x4 acc[M_REP][4] = {};
  bf16x8 a[MH][2], b[4][2];

#define STAGE_AU(S, U, P)                                                   \
  async16(aSrcB + ((size_t)((U) * 64) * K + (size_t)(S) * 64),              \
          &lds[(P) * BUFSZ + (U) * AH + t * 16])
#define STAGE_BU(S, U, P) do {                                              \
    _Pragma("unroll") for (int j = 0; j < 2; ++j)                           \
      async16(bSrcB + ((size_t)((U) * 128 + j * 64) * K + (size_t)(S) * 64),\
              &lds[(P) * BUFSZ + ABYTES + (U) * 16384 + j * 8192 + t * 16]);\
  } while (0)
#define LOAD_A(MHh, P)                                                      \
  _Pragma("unroll") for (int mi = 0; mi < MH; ++mi)                         \
  _Pragma("unroll") for (int ks = 0; ks < 2; ++ks)                          \
    a[mi][ks] = __builtin_bit_cast(bf16x8, *(const s16x8*)&lds[             \
        (P) * BUFSZ + ((aRd + ((MHh) * MH + mi) * 2048) ^ (ks << 6))])
#define LOAD_B(NHh, P)                                                      \
  _Pragma("unroll") for (int nn = 0; nn < 2; ++nn)                          \
  _Pragma("unroll") for (int ks = 0; ks < 2; ++ks)                          \
    b[(NHh) * 2 + nn][ks] = __builtin_bit_cast(bf16x8, *(const s16x8*)&lds[ \
        (P) * BUFSZ + ((bRd + ((NHh) * 2 + nn) * 2048) ^ (ks << 6))])
#define QUAD(MHh, NHh)                                                      \
  __builtin_amdgcn_s_setprio(1);                                            \
  _Pragma("unroll") for (int mi = 0; mi < MH; ++mi)                         \
  _Pragma("unroll") for (int nn = 0; nn < 2; ++nn)                          \
  _Pragma("unroll") for (int ks = 0; ks < 2; ++ks)                          \
    acc[(MHh) * MH + mi][(NHh) * 2 + nn] =                                  \
        __builtin_amdgcn_mfma_f32_16x16x32_bf16(                            \
            a[mi][ks], b[(NHh) * 2 + nn][ks],                               \
            acc[(MHh) * MH + mi][(NHh) * 2 + nn], 0, 0, 0);                 \
  __builtin_amdgcn_s_setprio(0)
#define BAR() __builtin_amdgcn_s_barrier()
#define LG0() asm volatile("s_waitcnt lgkmcnt(0)" ::: "memory")
#define TILE(T, P) do {                                                     \
    LOAD_A(0, P); LOAD_B(0, P);                                             \
    if ((T) + 1 < NT) STAGE_AU((T) + 1, 0, (P) ^ 1);                        \
    BAR(); LG0(); QUAD(0, 0); BAR();                                        \
    LOAD_B(1, P);                                                           \
    if ((T) + 1 < NT) STAGE_AU((T) + 1, 1, (P) ^ 1);                        \
    BAR(); LG0(); QUAD(0, 1); BAR();                                        \
    LOAD_A(1, P);                                                           \
    if ((T) + 2 < NT) STAGE_BU((T) + 2, 0, P);                              \
    BAR(); LG0(); QUAD(1, 1); BAR();                                        \
    if ((T) + 2 < NT) STAGE_BU((T) + 2, 1, P);                              \
    BAR(); QUAD(1, 0);                                                      \
    if ((T) + 2 < NT) {                                                     \
      asm volatile("s_waitcnt vmcnt(4)" ::: "memory");                      \
    } else if ((T) + 1 < NT) {                                              \
      asm volatile("s_waitcnt vmcnt(0)" ::: "memory");                      \
    }                                                                       \
    BAR();                                                                  \
  } while (0)

  STAGE_AU(0, 0, 0); STAGE_AU(0, 1, 0);
  STAGE_BU(0, 0, 0); STAGE_BU(0, 1, 0);
  STAGE_BU(1, 0, 1); STAGE_BU(1, 1, 1);
  asm volatile("s_waitcnt vmcnt(4)" ::: "memory");
  BAR();

  for (int T = 0; T < NT; T += 2) {
    TILE(T, 0);
    TILE(T + 1, 1);
  }
#undef TILE
#undef QUAD
#undef LOAD_A
#undef LOAD_B
#undef STAGE_AU
#undef STAGE_BU
#undef BAR

  // ---- full-line fp32 epilogue via per-wave 4KB scratch ----
  const int ocol0 = colBase + wc * 64 + lr;
  float bvv[4];
#pragma unroll
  for (int ni = 0; ni < 4; ++ni) bvv[ni] = bias[ocol0 + ni * 16];
  const int SB = 2 * BUFSZ + wid * 4096;
  const int orowB = rowBase + wr * WROWS;
  const int rd = lane >> 3;                  // 0..7
  const int bo = (lane & 7) * 16;            // 0..112
#pragma unroll
  for (int mi = 0; mi < M_REP; ++mi) {
#pragma unroll
    for (int ni = 0; ni < 4; ++ni) {
#pragma unroll
      for (int r = 0; r < 4; ++r) {
        int row16 = lg * 4 + r;
        int ad = SB + row16 * 256 +
                 (((ni * 16 + lr) * 4) ^ ((row16 & 7) << 4));
        *(float*)&lds[ad] = acc[mi][ni][r] + bvv[ni];
      }
    }
    asm volatile("s_waitcnt lgkmcnt(0)" ::: "memory");
    f32x4 v00 = *(const f32x4*)&lds[SB + rd * 256 + (bo ^ ((rd & 7) << 4))];
    f32x4 v01 = *(const f32x4*)&lds[SB + rd * 256 +
                                    ((bo + 128) ^ ((rd & 7) << 4))];
    f32x4 v10 = *(const f32x4*)&lds[SB + (rd + 8) * 256 +
                                    (bo ^ ((rd & 7) << 4))];
    f32x4 v11 = *(const f32x4*)&lds[SB + (rd + 8) * 256 +
                                    ((bo + 128) ^ ((rd & 7) << 4))];
    float* dst0 = Cout + (size_t)(orowB + mi * 16 + rd) * N +
                  colBase + wc * 64 + (lane & 7) * 4;
    *(f32x4*)dst0 = v00;
    *(f32x4*)(dst0 + 32) = v01;
    float* dst1 = dst0 + (size_t)8 * N;
    *(f32x4*)dst1 = v10;
    *(f32x4*)(dst1 + 32) = v11;
    asm volatile("s_waitcnt lgkmcnt(0)" ::: "memory");
  }
}

// ---------------- launch ----------------

extern "C" void kernel_launch(void* const* d_in, const int* in_sizes, int n_in,
                              void* d_out, int out_size, void* d_ws,
                              size_t ws_size, hipStream_t stream) {
  const float* x     = (const float*)d_in[0];
  const float* W1    = (const float*)d_in[1];
  const float* b1    = (const float*)d_in[2];
  const float* theta = (const float*)d_in[3];
  const float* qwr   = (const float*)d_in[4];
  const float* qwi   = (const float*)d_in[5];
  const float* W2    = (const float*)d_in[6];
  const float* b2    = (const float*)d_in[7];
  float* out = (float*)d_out;

  const int DF = 4096;
  size_t need = ((size_t)96 << 20) + DF * sizeof(float);
  if (ws_size < need) return;

  char* ws = (char*)d_ws;
  unsigned short* xb   = (unsigned short*)ws;                          // 16 MiB
  unsigned short* w1t  = (unsigned short*)(ws + ((size_t)16 << 20));   //  8 MiB
  unsigned short* w2t  = (unsigned short*)(ws + ((size_t)24 << 20));   //  8 MiB
  unsigned short* actb = (unsigned short*)(ws + ((size_t)32 << 20));   // 64 MiB
  float* c1 = (float*)(ws + ((size_t)96 << 20));

  prep<<<9232, 256, 0, stream>>>(x, W1, W2, theta, qwr, qwi,
                                 xb, w1t, w2t, c1);
  gemm1k<<<256, 512, 0, stream>>>(xb, w1t, b1, theta, c1, actb);
  gemm2k<<<256, 512, 0, stream>>>(actb, w2t, b2, out);
}

// Round 15
// 146.831 us; speedup vs baseline: 1.4258x; 1.4258x over previous
//
#include <hip/hip_runtime.h>

typedef __bf16 bf16x8 __attribute__((ext_vector_type(8)));
typedef short  s16x8  __attribute__((ext_vector_type(8)));
typedef float  f32x4  __attribute__((ext_vector_type(4)));

#define DEVINL __device__ __forceinline__

DEVINL unsigned short f2bf(float f) {
  unsigned int u = __builtin_bit_cast(unsigned int, f);
  u += 0x7fffu + ((u >> 16) & 1u);   // round-to-nearest-even
  return (unsigned short)(u >> 16);
}

DEVINL void async16(const void* g, void* l) {
  __builtin_amdgcn_global_load_lds(
      (const __attribute__((address_space(1))) unsigned int*)g,
      (__attribute__((address_space(3))) unsigned int*)l, 16, 0, 0);
}

// ---------------- fused prep kernel ----------------

__global__ __launch_bounds__(256) void prep(
    const float* __restrict__ x, const float* __restrict__ W1,
    const float* __restrict__ W2, const float* __restrict__ theta,
    const float* __restrict__ wre, const float* __restrict__ wim,
    unsigned short* __restrict__ xb, unsigned short* __restrict__ w1t,
    unsigned short* __restrict__ w2t, float* __restrict__ c1) {
  __shared__ unsigned short tile[32][33];
  const int b = blockIdx.x;
  const int tid = threadIdx.x;
  if (b < 1024) {
    int i = b * 256 + tid;
#pragma unroll
    for (int k = 0; k < 8; ++k, i += 262144) {
      float4 v = ((const float4*)x)[i];
      ushort4 o;
      o.x = f2bf(v.x); o.y = f2bf(v.y); o.z = f2bf(v.z); o.w = f2bf(v.w);
      ((ushort4*)xb)[i] = o;
    }
  } else if (b < 5120) {
    int bb = b - 1024;                      // W1: R=1024, C=4096
    int bc = (bb & 127) * 32, br = (bb >> 7) * 32;
    int tx = tid & 31, ty = tid >> 5;
#pragma unroll
    for (int i = 0; i < 32; i += 8)
      tile[ty + i][tx] = f2bf(W1[(size_t)(br + ty + i) * 4096 + (bc + tx)]);
    __syncthreads();
#pragma unroll
    for (int i = 0; i < 32; i += 8)
      w1t[(size_t)(bc + ty + i) * 1024 + (br + tx)] = tile[tx][ty + i];
  } else if (b < 9216) {
    int bb = b - 5120;                      // W2: R=4096, C=1024
    int bc = (bb & 31) * 32, br = (bb >> 5) * 32;
    int tx = tid & 31, ty = tid >> 5;
#pragma unroll
    for (int i = 0; i < 32; i += 8)
      tile[ty + i][tx] = f2bf(W2[(size_t)(br + ty + i) * 1024 + (bc + tx)]);
    __syncthreads();
#pragma unroll
    for (int i = 0; i < 32; i += 8)
      w2t[(size_t)(bc + ty + i) * 4096 + (br + tx)] = tile[tx][ty + i];
  } else {
    int i = (b - 9216) * 256 + tid;         // qconst, n = 4096
    float t = theta[i];
    c1[i] = (cosf(t) * wre[i] + sinf(t) * wim[i]) * wim[i] * 0.1f;
  }
}

// ================= GEMM1: actb = relu(qt(xb @ w1t^T + b1)) =================
// R13 verbatim (best measured: 73 us, 0 conflicts, no spill).
// 256x256 tile, BK=64, NT=16, REPS=2, 2-barrier window schedule.

__global__ __launch_bounds__(512, 1) void gemm1k(
    const unsigned short* __restrict__ A,    // xb  [8192][1024]
    const unsigned short* __restrict__ Bt,   // w1t [4096][1024]
    const float* __restrict__ bias,
    const float* __restrict__ theta,
    const float* __restrict__ c1,
    unsigned short* __restrict__ Cout) {     // actb [8192][4096]
  constexpr int K = 1024, N = 4096, NT = 16, REPS = 2;
  constexpr int WROWS = 128, M_REP = 8, MH = 4;
  constexpr int ABYTES = 32768, AH = 16384, AL = 2;
  constexpr int BUFSZ = 65536;
  constexpr int nTilesN = 8;                 // 4096 / 512

  __shared__ __align__(16) char lds[2 * BUFSZ + 16384];

  int nwg = gridDim.x;
  int wg = blockIdx.x;
  int sw = (wg & 7) * (nwg >> 3) + (wg >> 3);
  int rowBase = (sw / nTilesN) * 256;
  int colBase = (sw % nTilesN) * 512;

  const int t = threadIdx.x;
  const int lane = t & 63;
  const int wid = t >> 6;
  const int wr = wid >> 2, wc = wid & 3;
  const int lr = lane & 15;
  const int lg = lane >> 4;
  const int r7 = lane & 7;

  const int srow = t >> 3;
  const int scolB = ((t & 7) * 16) ^ ((srow & 7) << 4);
  const unsigned short* aSrcB = A  + (size_t)(rowBase + srow) * K + (scolB >> 1);
  const unsigned short* bSrcB = Bt + (size_t)(colBase + srow) * K + (scolB >> 1);

  const int aRd = (wr * WROWS + lr) * 128 + ((lg ^ r7) << 4);
  const int bRd = ABYTES + (wc * 64 + lr) * 128 + ((lg ^ r7) << 4);

#define STAGE_AU(S, U, P) do {                                              \
    _Pragma("unroll") for (int j = 0; j < AL; ++j)                          \
      async16(aSrcB + ((size_t)((U) * WROWS + j * 64) * K + (size_t)(S) * 64),\
              &lds[(P) * BUFSZ + (U) * AH + j * 8192 + t * 16]);            \
  } while (0)
#define STAGE_BU(SRC, S, U, P) do {                                         \
    _Pragma("unroll") for (int j = 0; j < 2; ++j)                           \
      async16((SRC) + ((size_t)((U) * 128 + j * 64) * K + (size_t)(S) * 64),\
              &lds[(P) * BUFSZ + ABYTES + (U) * 16384 + j * 8192 + t * 16]);\
  } while (0)
#define LOAD_A(MHh, P)                                                      \
  _Pragma("unroll") for (int mi = 0; mi < MH; ++mi)                         \
  _Pragma("unroll") for (int ks = 0; ks < 2; ++ks)                          \
    a[mi][ks] = __builtin_bit_cast(bf16x8, *(const s16x8*)&lds[             \
        (P) * BUFSZ + ((aRd + ((MHh) * MH + mi) * 2048) ^ (ks << 6))])
#define LOAD_B(NHh, P)                                                      \
  _Pragma("unroll") for (int nn = 0; nn < 2; ++nn)                          \
  _Pragma("unroll") for (int ks = 0; ks < 2; ++ks)                          \
    b[(NHh) * 2 + nn][ks] = __builtin_bit_cast(bf16x8, *(const s16x8*)&lds[ \
        (P) * BUFSZ + ((bRd + ((NHh) * 2 + nn) * 2048) ^ (ks << 6))])
#define QUAD(MHh, NHh)                                                      \
  __builtin_amdgcn_s_setprio(1);                                            \
  _Pragma("unroll") for (int mi = 0; mi < MH; ++mi)                         \
  _Pragma("unroll") for (int nn = 0; nn < 2; ++nn)                          \
  _Pragma("unroll") for (int ks = 0; ks < 2; ++ks)                          \
    acc[(MHh) * MH + mi][(NHh) * 2 + nn] =                                  \
        __builtin_amdgcn_mfma_f32_16x16x32_bf16(                            \
            a[mi][ks], b[(NHh) * 2 + nn][ks],                               \
            acc[(MHh) * MH + mi][(NHh) * 2 + nn], 0, 0, 0);                 \
  __builtin_amdgcn_s_setprio(0)
#define BAR() __builtin_amdgcn_s_barrier()
#define LG0() asm volatile("s_waitcnt lgkmcnt(0)" ::: "memory")
#define WIN(T, P) do {                                                      \
    /* half 1 */                                                            \
    LOAD_A(0, P); LOAD_B(0, P);                                             \
    if ((T) + 1 < NT) {                                                     \
      STAGE_AU((T) + 1, 0, (P) ^ 1);                                        \
      STAGE_AU((T) + 1, 1, (P) ^ 1);                                        \
    }                                                                       \
    QUAD(0, 0);                                                             \
    LOAD_B(1, P);                                                           \
    QUAD(0, 1);                                                             \
    LG0(); BAR();                                                           \
    /* half 2 */                                                            \
    LOAD_A(1, P);                                                           \
    if ((T) + 2 < NT) {                                                     \
      STAGE_BU(bSrcR, (T) + 2, 0, P);                                       \
      STAGE_BU(bSrcR, (T) + 2, 1, P);                                       \
    }                                                                       \
    QUAD(1, 0);                                                             \
    QUAD(1, 1);                                                             \
    LG0();                                                                  \
    if ((T) < NT - 2) {                                                     \
      asm volatile("s_waitcnt vmcnt(4)" ::: "memory");                      \
    } else if ((T) == NT - 2) {                                             \
      asm volatile("s_waitcnt vmcnt(0)" ::: "memory");                      \
    }                                                                       \
    BAR();                                                                  \
  } while (0)

  STAGE_AU(0, 0, 0); STAGE_AU(0, 1, 0);
  STAGE_BU(bSrcB, 0, 0, 0); STAGE_BU(bSrcB, 0, 1, 0);
  STAGE_BU(bSrcB, 1, 0, 1); STAGE_BU(bSrcB, 1, 1, 1);
  asm volatile("s_waitcnt vmcnt(4)" ::: "memory");
  BAR();

  for (int rep = 0; rep < REPS; ++rep) {
    const unsigned short* bSrcR = bSrcB + (size_t)rep * 256 * K;
    f32x4 acc[M_REP][4] = {};
    bf16x8 a[MH][2], b[4][2];

    for (int T = 0; T < NT; T += 2) {
      WIN(T, 0);
      WIN(T + 1, 1);
    }

    if (rep + 1 < REPS) {
      const unsigned short* bSrcN = bSrcB + (size_t)(rep + 1) * 256 * K;
      STAGE_AU(0, 0, 0); STAGE_AU(0, 1, 0);
      STAGE_BU(bSrcN, 0, 0, 0); STAGE_BU(bSrcN, 0, 1, 0);
      STAGE_BU(bSrcN, 1, 0, 1); STAGE_BU(bSrcN, 1, 1, 1);
    }

    // ---- fused epilogue (bias + quantum + relu), full-line bf16 stores ----
    const int colR = colBase + rep * 256;
    const int ocol0 = colR + wc * 64 + lr;
    float bvv[4], thv[4], ccv[4];
#pragma unroll
    for (int ni = 0; ni < 4; ++ni) {
      int n = ocol0 + ni * 16;
      bvv[ni] = bias[n]; thv[ni] = theta[n]; ccv[ni] = c1[n];
    }
    const int SB = 2 * BUFSZ + wid * 2048;
    const size_t growB = (size_t)(rowBase + wr * WROWS) * N;
    const int rd = lane >> 3;                // 0..7
    const int bo = (lane & 7) * 16;          // 0..112
#pragma unroll
    for (int mi = 0; mi < M_REP; ++mi) {
#pragma unroll
      for (int ni = 0; ni < 4; ++ni) {
#pragma unroll
        for (int r = 0; r < 4; ++r) {
          int row16 = lg * 4 + r;
          float h = acc[mi][ni][r] + bvv[ni];
          float q = h + ccv[ni] * __sinf(thv[ni] + 0.1f * h);
          unsigned short v = f2bf(fmaxf(q, 0.f));
          int ad = SB + row16 * 128 +
                   (((ni * 16 + lr) * 2) ^ ((row16 & 7) << 4));
          *(unsigned short*)&lds[ad] = v;
        }
      }
      s16x8 w0 = *(const s16x8*)&lds[SB + rd * 128 + (bo ^ ((rd & 7) << 4))];
      s16x8 w1 = *(const s16x8*)&lds[SB + (rd + 8) * 128 +
                                     (bo ^ ((rd & 7) << 4))];
      unsigned short* dst = Cout + growB + (size_t)(mi * 16 + rd) * N +
                            colR + wc * 64 + (lane & 7) * 8;
      *(s16x8*)dst = w0;
      *(s16x8*)(dst + (size_t)8 * N) = w1;   // rows rd and rd+8
    }

    if (rep + 1 < REPS) {
      asm volatile("s_waitcnt vmcnt(16)" ::: "memory");
      BAR();
    }
  }
#undef WIN
#undef QUAD
#undef LOAD_A
#undef LOAD_B
#undef STAGE_AU
#undef STAGE_BU
#undef BAR
#undef LG0
}

// ================= GEMM2: out = actb @ w2t^T + b2 (fp32) =================
// 128x256 tile, BK=64, NT=64. R15: ported to the 2-barrier window schedule
// (GEMM1's R13 A/B showed -7% vs the 8-barrier loop; GEMM2 was 827 cy/tile
// over its LDS floor with 8 barriers).
// Ledger (AL=1): half1 stages A(T+1) (2 loads) -> P^1; half2 stages B(T+2)
// (4 loads) -> P. At half2's wait, FIFO = [A(T+1)x2, B(T+2)x4] -> vmcnt(4)
// certifies A(T+1); B(T+1) (staged in window T-1 half2) is older -> also
// certified. WAR: buf P^1's A read (LOAD_A in window T-1) drained by that
// window's LG0s before its BARs; buf P's B reads drained by half1's LG0.
// Prologue FIFO: [A(0)x2, B(0)x4, B(1)x4] -> vmcnt(4) drains tile 0.

__global__ __launch_bounds__(512, 1) void gemm2k(
    const unsigned short* __restrict__ A,    // actb [8192][4096]
    const unsigned short* __restrict__ Bt,   // w2t  [1024][4096]
    const float* __restrict__ bias,
    float* __restrict__ Cout) {              // out [8192][1024]
  constexpr int K = 4096, N = 1024, NT = 64;
  constexpr int WROWS = 64, M_REP = 4, MH = 2;
  constexpr int ABYTES = 16384, AH = 8192, AL = 1;
  constexpr int BUFSZ = 49152;
  constexpr int nTilesN = 4;

  __shared__ __align__(16) char lds[2 * BUFSZ + 32768];

  int nwg = gridDim.x;
  int wg = blockIdx.x;
  int sw = (wg & 7) * (nwg >> 3) + (wg >> 3);
  int rowBase = (sw / nTilesN) * 128;
  int colBase = (sw % nTilesN) * 256;

  const int t = threadIdx.x;
  const int lane = t & 63;
  const int wid = t >> 6;
  const int wr = wid >> 2, wc = wid & 3;
  const int lr = lane & 15;
  const int lg = lane >> 4;
  const int r7 = lane & 7;

  const int srow = t >> 3;
  const int scolB = ((t & 7) * 16) ^ ((srow & 7) << 4);
  const unsigned short* aSrcB = A  + (size_t)(rowBase + srow) * K + (scolB >> 1);
  const unsigned short* bSrcB = Bt + (size_t)(colBase + srow) * K + (scolB >> 1);

  const int aRd = (wr * WROWS + lr) * 128 + ((lg ^ r7) << 4);
  const int bRd = ABYTES + (wc * 64 + lr) * 128 + ((lg ^ r7) << 4);

  f32x4 acc[M_REP][4] = {};
  bf16x8 a[MH][2], b[4][2];

#define STAGE_AU(S, U, P)                                                   \
  async16(aSrcB + ((size_t)((U) * 64) * K + (size_t)(S) * 64),              \
          &lds[(P) * BUFSZ + (U) * AH + t * 16])
#define STAGE_BU(S, U, P) do {                                              \
    _Pragma("unroll") for (int j = 0; j < 2; ++j)                           \
      async16(bSrcB + ((size_t)((U) * 128 + j * 64) * K + (size_t)(S) * 64),\
              &lds[(P) * BUFSZ + ABYTES + (U) * 16384 + j * 8192 + t * 16]);\
  } while (0)
#define LOAD_A(MHh, P)                                                      \
  _Pragma("unroll") for (int mi = 0; mi < MH; ++mi)                         \
  _Pragma("unroll") for (int ks = 0; ks < 2; ++ks)                          \
    a[mi][ks] = __builtin_bit_cast(bf16x8, *(const s16x8*)&lds[             \
        (P) * BUFSZ + ((aRd + ((MHh) * MH + mi) * 2048) ^ (ks << 6))])
#define LOAD_B(NHh, P)                                                      \
  _Pragma("unroll") for (int nn = 0; nn < 2; ++nn)                          \
  _Pragma("unroll") for (int ks = 0; ks < 2; ++ks)                          \
    b[(NHh) * 2 + nn][ks] = __builtin_bit_cast(bf16x8, *(const s16x8*)&lds[ \
        (P) * BUFSZ + ((bRd + ((NHh) * 2 + nn) * 2048) ^ (ks << 6))])
#define QUAD(MHh, NHh)                                                      \
  __builtin_amdgcn_s_setprio(1);                                            \
  _Pragma("unroll") for (int mi = 0; mi < MH; ++mi)                         \
  _Pragma("unroll") for (int nn = 0; nn < 2; ++nn)                          \
  _Pragma("unroll") for (int ks = 0; ks < 2; ++ks)                          \
    acc[(MHh) * MH + mi][(NHh) * 2 + nn] =                                  \
        __builtin_amdgcn_mfma_f32_16x16x32_bf16(                            \
            a[mi][ks], b[(NHh) * 2 + nn][ks],                               \
            acc[(MHh) * MH + mi][(NHh) * 2 + nn], 0, 0, 0);                 \
  __builtin_amdgcn_s_setprio(0)
#define BAR() __builtin_amdgcn_s_barrier()
#define LG0() asm volatile("s_waitcnt lgkmcnt(0)" ::: "memory")
#define WIN(T, P) do {                                                      \
    /* half 1 */                                                            \
    LOAD_A(0, P); LOAD_B(0, P);                                             \
    if ((T) + 1 < NT) {                                                     \
      STAGE_AU((T) + 1, 0, (P) ^ 1);                                        \
      STAGE_AU((T) + 1, 1, (P) ^ 1);                                        \
    }                                                                       \
    QUAD(0, 0);                                                             \
    LOAD_B(1, P);                                                           \
    QUAD(0, 1);                                                             \
    LG0(); BAR();                                                           \
    /* half 2 */                                                            \
    LOAD_A(1, P);                                                           \
    if ((T) + 2 < NT) {                                                     \
      STAGE_BU((T) + 2, 0, P);                                              \
      STAGE_BU((T) + 2, 1, P);                                              \
    }                                                                       \
    QUAD(1, 0);                                                             \
    QUAD(1, 1);                                                             \
    LG0();                                                                  \
    if ((T) < NT - 2) {                                                     \
      asm volatile("s_waitcnt vmcnt(4)" ::: "memory");                      \
    } else if ((T) == NT - 2) {                                             \
      asm volatile("s_waitcnt vmcnt(0)" ::: "memory");                      \
    }                                                                       \
    BAR();                                                                  \
  } while (0)

  STAGE_AU(0, 0, 0); STAGE_AU(0, 1, 0);
  STAGE_BU(0, 0, 0); STAGE_BU(0, 1, 0);
  STAGE_BU(1, 0, 1); STAGE_BU(1, 1, 1);
  asm volatile("s_waitcnt vmcnt(4)" ::: "memory");
  BAR();

  for (int T = 0; T < NT; T += 2) {
    WIN(T, 0);
    WIN(T + 1, 1);
  }
#undef WIN
#undef QUAD
#undef LOAD_A
#undef LOAD_B
#undef STAGE_AU
#undef STAGE_BU
#undef BAR

  // ---- full-line fp32 epilogue via per-wave 4KB scratch ----
  const int ocol0 = colBase + wc * 64 + lr;
  float bvv[4];
#pragma unroll
  for (int ni = 0; ni < 4; ++ni) bvv[ni] = bias[ocol0 + ni * 16];
  const int SB = 2 * BUFSZ + wid * 4096;
  const int orowB = rowBase + wr * WROWS;
  const int rd = lane >> 3;                  // 0..7
  const int bo = (lane & 7) * 16;            // 0..112
#pragma unroll
  for (int mi = 0; mi < M_REP; ++mi) {
#pragma unroll
    for (int ni = 0; ni < 4; ++ni) {
#pragma unroll
      for (int r = 0; r < 4; ++r) {
        int row16 = lg * 4 + r;
        int ad = SB + row16 * 256 +
                 (((ni * 16 + lr) * 4) ^ ((row16 & 7) << 4));
        *(float*)&lds[ad] = acc[mi][ni][r] + bvv[ni];
      }
    }
    asm volatile("s_waitcnt lgkmcnt(0)" ::: "memory");
    f32x4 v00 = *(const f32x4*)&lds[SB + rd * 256 + (bo ^ ((rd & 7) << 4))];
    f32x4 v01 = *(const f32x4*)&lds[SB + rd * 256 +
                                    ((bo + 128) ^ ((rd & 7) << 4))];
    f32x4 v10 = *(const f32x4*)&lds[SB + (rd + 8) * 256 +
                                    (bo ^ ((rd & 7) << 4))];
    f32x4 v11 = *(const f32x4*)&lds[SB + (rd + 8) * 256 +
                                    ((bo + 128) ^ ((rd & 7) << 4))];
    float* dst0 = Cout + (size_t)(orowB + mi * 16 + rd) * N +
                  colBase + wc * 64 + (lane & 7) * 4;
    *(f32x4*)dst0 = v00;
    *(f32x4*)(dst0 + 32) = v01;
    float* dst1 = dst0 + (size_t)8 * N;
    *(f32x4*)dst1 = v10;
    *(f32x4*)(dst1 + 32) = v11;
    asm volatile("s_waitcnt lgkmcnt(0)" ::: "memory");
  }
#undef LG0
}

// ---------------- launch ----------------

extern "C" void kernel_launch(void* const* d_in, const int* in_sizes, int n_in,
                              void* d_out, int out_size, void* d_ws,
                              size_t ws_size, hipStream_t stream) {
  const float* x     = (const float*)d_in[0];
  const float* W1    = (const float*)d_in[1];
  const float* b1    = (const float*)d_in[2];
  const float* theta = (const float*)d_in[3];
  const float* qwr   = (const float*)d_in[4];
  const float* qwi   = (const float*)d_in[5];
  const float* W2    = (const float*)d_in[6];
  const float* b2    = (const float*)d_in[7];
  float* out = (float*)d_out;

  const int DF = 4096;
  size_t need = ((size_t)96 << 20) + DF * sizeof(float);
  if (ws_size < need) return;

  char* ws = (char*)d_ws;
  unsigned short* xb   = (unsigned short*)ws;                          // 16 MiB
  unsigned short* w1t  = (unsigned short*)(ws + ((size_t)16 << 20));   //  8 MiB
  unsigned short* w2t  = (unsigned short*)(ws + ((size_t)24 << 20));   //  8 MiB
  unsigned short* actb = (unsigned short*)(ws + ((size_t)32 << 20));   // 64 MiB
  float* c1 = (float*)(ws + ((size_t)96 << 20));

  prep<<<9232, 256, 0, stream>>>(x, W1, W2, theta, qwr, qwi,
                                 xb, w1t, w2t, c1);
  gemm1k<<<256, 512, 0, stream>>>(xb, w1t, b1, theta, c1, actb);
  gemm2k<<<256, 512, 0, stream>>>(actb, w2t, b2, out);
}